// Round 11
// baseline (138.417 us; speedup 1.0000x reference)
//
#include <hip/hip_runtime.h>
#include <hip/hip_bf16.h>

#define NPTS   1024
#define HID    128
#define K_TAB  512            // lerp intervals over u = log2(d) in [U0, U1]
#define NPASS  9              // 9 passes x 64 entries = 576 slots >= K_TAB+1
#define U0f    (-10.0f)
#define U1f    (4.0f)
#define LDH    136            // padded k-stride (bf16) for the W2^T LDS tile

typedef __bf16 bf16_t;
typedef __bf16 bf16x8 __attribute__((ext_vector_type(8)));
typedef float  f32x4  __attribute__((ext_vector_type(4)));

__device__ __forceinline__ float fast_exp2(float x) {
#if __has_builtin(__builtin_amdgcn_exp2f)
    return __builtin_amdgcn_exp2f(x);
#else
    return exp2f(x);
#endif
}
__device__ __forceinline__ float fast_rcp(float x) {
#if __has_builtin(__builtin_amdgcn_rcpf)
    return __builtin_amdgcn_rcpf(x);
#else
    return 1.0f / x;
#endif
}
__device__ __forceinline__ float fast_log2(float x) {
#if __has_builtin(__builtin_amdgcn_logf)
    return __builtin_amdgcn_logf(x);
#else
    return __log2f(x);
#endif
}
__device__ __forceinline__ float fast_rsq(float x) {
#if __has_builtin(__builtin_amdgcn_rsqf)
    return __builtin_amdgcn_rsqf(x);
#else
    return rsqrtf(x);
#endif
}
// tanh(x) = 1 - 2/(e^{2x}+1). Saturates correctly at +-inf.
__device__ __forceinline__ float fast_tanh(float x) {
    float e = fast_exp2(2.8853900817779268f * x);
    return 1.0f - 2.0f * fast_rcp(e + 1.0f);
}

// One plain kernel, no workspace, one graph node.
// 512 blocks (2/CU) x 256 threads (4 waves -> 2 waves/SIMD).
// KEY CHANGE vs R9/R10: W2 B-fragments are NOT register-cached. They are
// re-read from the live sW LDS tile at each MFMA (32 ds_read_b128 per
// pass per wave, ~400 cyc — noise). R9/R10 proved the 128-reg wfrag
// cannot coexist with 2 waves/SIMD (compiler spills: 76/143 MB scratch).
// Stage 1 (redundant per block): mag(d) table via MFMA, A-frags in regs.
// Stage 2: 8 i-rows per block (2 per wave), table-lerp force accumulation.
__launch_bounds__(256, 2)
__global__ void discovery_one(const float* __restrict__ pos,
                              const float* __restrict__ W1,
                              const float* __restrict__ b1,
                              const float* __restrict__ W2,
                              const float* __restrict__ b2,
                              const float* __restrict__ W3,
                              const float* __restrict__ b3,
                              float* __restrict__ out)
{
    __shared__ __align__(16) bf16_t sW[HID * LDH];        // W2^T (34.8 KB, live all of stage 1)
    __shared__ __align__(16) float  tab_s[NPASS * 64 + 4];// 2.3 KB (580 slots, 513 live)
    __shared__ float  pos_s[NPTS * 3];                    // 12 KB
    __shared__ f32x4  w1s[HID];                           // (W1[0,h],W1[1,h],W1[2,h],b1[h])
    __shared__ float  b2s[HID];
    __shared__ float  w3s[HID];

    const int t    = threadIdx.x;       // 0..255
    const int wave = t >> 6;            // 0..3
    const int lane = t & 63;
    const int ln   = lane & 15;
    const int q    = lane >> 4;

    const int b  = blockIdx.x >> 7;     // 128 blocks per batch
    const int ig = blockIdx.x & 127;    // 8 i's per block

    // ---------------- preamble ----------------
    {
        const float4* gp = (const float4*)(pos + b * NPTS * 3);
        float4* sp = (float4*)pos_s;
        for (int idx = t; idx < NPTS * 3 / 4; idx += 256) sp[idx] = gp[idx];
    }
    if (t < HID) {
        f32x4 w = { W1[t], W1[HID + t], W1[2 * HID + t], b1[t] };
        w1s[t] = w;
        b2s[t] = b2[t];
        w3s[t] = W3[t];
    }
    // stage W2 transposed (bf16): sW[n*LDH + k] = W2[k*HID + n]
    for (int idx = t; idx < HID * HID; idx += 256) {
        int k = idx >> 7, n = idx & 127;
        sW[n * LDH + k] = (bf16_t)W2[idx];
    }
    __syncthreads();

    const float dU  = (U1f - U0f) / (float)K_TAB;
    const float b3v = b3[0];
    const bf16_t* wbase = &sW[ln * LDH + q * 8];   // B-frag base for (ln, q)

    // ---------------- Stage 1: table build, 9 passes x 64 entries ----------------
    for (int p = 0; p < NPASS; ++p) {
        const int base = p * 64 + wave * 16;              // this wave's 16 entries
        // geometry for entry m = ln (clamped beyond K_TAB -> g(U1), never read)
        int   ec   = base + ln; if (ec > K_TAB) ec = K_TAB;
        float u    = U0f + (float)ec * dU;
        float d    = fast_exp2(u);
        float invc = fast_rcp(fmaxf(d, 0.01f));
        float inv2 = invc * invc;

        // A-fragments in registers: afr[ks][j] = tanh-h1[entry ln][unit ks*32+q*8+j]
        bf16x8 afr[4];
#pragma unroll
        for (int ks = 0; ks < 4; ++ks) {
#pragma unroll
            for (int j = 0; j < 8; ++j) {
                f32x4 w = w1s[ks * 32 + q * 8 + j];
                float z = fmaf(d, w[0], fmaf(invc, w[1], fmaf(inv2, w[2], w[3])));
                afr[ks][j] = (bf16_t)fast_tanh(z);
            }
        }

        // h2pre = h1 @ W2 : one 16(entry) x 128(unit) tile per wave.
        // B-frag (nt,ks) read straight from LDS: sW[(nt*16+ln)*LDH + ks*32 + q*8]
        f32x4 zero = { 0.f, 0.f, 0.f, 0.f };
        f32x4 acc[8];
#pragma unroll
        for (int nt = 0; nt < 8; ++nt) acc[nt] = zero;
#pragma unroll
        for (int ks = 0; ks < 4; ++ks) {
#pragma unroll
            for (int nt = 0; nt < 8; ++nt) {
                bf16x8 bf = *(const bf16x8*)(wbase + (nt * 16) * LDH + ks * 32);
                acc[nt] = __builtin_amdgcn_mfma_f32_16x16x32_bf16(afr[ks], bf, acc[nt], 0, 0, 0);
            }
        }

        // epilogue: tab = tanh(h2pre + b2) @ W3 + b3
        float pm[4] = {0.f, 0.f, 0.f, 0.f};
#pragma unroll
        for (int nt = 0; nt < 8; ++nt) {
            float b2n = b2s[nt * 16 + ln];
            float w3n = w3s[nt * 16 + ln];
#pragma unroll
            for (int r = 0; r < 4; ++r)
                pm[r] += fast_tanh(acc[nt][r] + b2n) * w3n;
        }
#pragma unroll
        for (int off = 1; off < 16; off <<= 1)
#pragma unroll
            for (int r = 0; r < 4; ++r)
                pm[r] += __shfl_xor(pm[r], off);
        if (ln == 0) {
            // C rows q*4+r = entry offsets within this wave's 16-entry group
            f32x4 v = { pm[0] + b3v, pm[1] + b3v, pm[2] + b3v, pm[3] + b3v };
            *(f32x4*)&tab_s[base + q * 4] = v;            // max index 575 < 580
        }
    }
    __syncthreads();   // table complete

    // ---------------- Stage 2: forces (2 i's per wave) ----------------
    const float S  = (float)K_TAB / (U1f - U0f);
    const int   ia = ig * 8 + wave * 2;
    const int   ib = ia + 1;

    const float pax = pos_s[ia * 3 + 0], pay = pos_s[ia * 3 + 1], paz = pos_s[ia * 3 + 2];
    const float pbx = pos_s[ib * 3 + 0], pby = pos_s[ib * 3 + 1], pbz = pos_s[ib * 3 + 2];

    float fax = 0.f, fay = 0.f, faz = 0.f;
    float fbx = 0.f, fby = 0.f, fbz = 0.f;
#pragma unroll 4
    for (int j = lane; j < NPTS; j += 64) {
        float qx = pos_s[j * 3 + 0], qy = pos_s[j * 3 + 1], qz = pos_s[j * 3 + 2];

        float dax = pax - qx, day = pay - qy, daz = paz - qz;
        float dbx = pbx - qx, dby = pby - qy, dbz = pbz - qz;
        float r2a = fmaf(dax, dax, fmaf(day, day, daz * daz));
        float r2b = fmaf(dbx, dbx, fmaf(dby, dby, dbz * dbz));

        float ta = fmaf(0.5f * fast_log2(r2a), S, -U0f * S);  // r2=0 -> -inf -> k=0
        float tb = fmaf(0.5f * fast_log2(r2b), S, -U0f * S);
        float ka = fminf(fmaxf(floorf(ta), 0.0f), (float)(K_TAB - 1));
        float kb = fminf(fmaxf(floorf(tb), 0.0f), (float)(K_TAB - 1));
        float fra = fminf(fmaxf(ta - ka, 0.0f), 1.0f);
        float frb = fminf(fmaxf(tb - kb, 0.0f), 1.0f);
        int ka_i = (int)ka, kb_i = (int)kb;
        float va0 = tab_s[ka_i], va1 = tab_s[ka_i + 1];
        float vb0 = tab_s[kb_i], vb1 = tab_s[kb_i + 1];
        float maga = fmaf(va1 - va0, fra, va0);
        float magb = fmaf(vb1 - vb0, frb, vb0);

        float sa = maga * fminf(fast_rsq(r2a), 100.0f);   // mag/max(d,0.01); rsq(0)=inf->100
        float sb = magb * fminf(fast_rsq(r2b), 100.0f);
        fax = fmaf(sa, dax, fax); fay = fmaf(sa, day, fay); faz = fmaf(sa, daz, faz);
        fbx = fmaf(sb, dbx, fbx); fby = fmaf(sb, dby, fby); fbz = fmaf(sb, dbz, fbz);
    }
#pragma unroll
    for (int off = 1; off < 64; off <<= 1) {
        fax += __shfl_xor(fax, off); fay += __shfl_xor(fay, off); faz += __shfl_xor(faz, off);
        fbx += __shfl_xor(fbx, off); fby += __shfl_xor(fby, off); fbz += __shfl_xor(fbz, off);
    }
    if (lane == 0) {
        int oa = (b * NPTS + ia) * 3;
        int ob = (b * NPTS + ib) * 3;
        out[oa + 0] = fax; out[oa + 1] = fay; out[oa + 2] = faz;
        out[ob + 0] = fbx; out[ob + 1] = fby; out[ob + 2] = fbz;
    }
}

extern "C" void kernel_launch(void* const* d_in, const int* in_sizes, int n_in,
                              void* d_out, int out_size, void* d_ws, size_t ws_size,
                              hipStream_t stream) {
    const float* pos = (const float*)d_in[0];
    const float* W1  = (const float*)d_in[1];
    const float* b1  = (const float*)d_in[2];
    const float* W2  = (const float*)d_in[3];
    const float* b2  = (const float*)d_in[4];
    const float* W3  = (const float*)d_in[5];
    const float* b3  = (const float*)d_in[6];
    float* out = (float*)d_out;

    int B = (in_sizes[0] / 3) / NPTS;
    discovery_one<<<B * 128, 256, 0, stream>>>(pos, W1, b1, W2, b2, W3, b3, out);
}

// Round 12
// 103.301 us; speedup vs baseline: 1.3399x; 1.3399x over previous
//
#include <hip/hip_runtime.h>
#include <hip/hip_bf16.h>

#define NPTS   1024
#define HID    128
#define K_TAB  512            // lerp intervals over u = log2(d) in [U0, U1]
#define NPASS  9              // 9 passes x 64 entries = 576 slots >= K_TAB+1
#define U0f    (-10.0f)
#define U1f    (4.0f)
#define LDH    136            // padded k-stride (bf16) for the W2^T LDS tile

typedef __bf16 bf16_t;
typedef __bf16 bf16x8 __attribute__((ext_vector_type(8)));
typedef float  f32x4  __attribute__((ext_vector_type(4)));

__device__ __forceinline__ float fast_exp2(float x) {
#if __has_builtin(__builtin_amdgcn_exp2f)
    return __builtin_amdgcn_exp2f(x);
#else
    return exp2f(x);
#endif
}
__device__ __forceinline__ float fast_rcp(float x) {
#if __has_builtin(__builtin_amdgcn_rcpf)
    return __builtin_amdgcn_rcpf(x);
#else
    return 1.0f / x;
#endif
}
__device__ __forceinline__ float fast_log2(float x) {
#if __has_builtin(__builtin_amdgcn_logf)
    return __builtin_amdgcn_logf(x);
#else
    return __log2f(x);
#endif
}
__device__ __forceinline__ float fast_rsq(float x) {
#if __has_builtin(__builtin_amdgcn_rsqf)
    return __builtin_amdgcn_rsqf(x);
#else
    return rsqrtf(x);
#endif
}
// tanh(x) = 1 - 2/(e^{2x}+1). Saturates correctly at +-inf.
__device__ __forceinline__ float fast_tanh(float x) {
    float e = fast_exp2(2.8853900817779268f * x);
    return 1.0f - 2.0f * fast_rcp(e + 1.0f);
}

// One plain kernel, no workspace, one graph node.
// 512 blocks (2/CU) x 256 threads (4 waves -> 2 waves/SIMD).
// R11 LESSON: without a fence inside the pass loop, LICM hoists the
// loop-invariant B-fragment ds_reads out of all 9 passes, re-creating the
// 128-reg cache R10 had -- and spills it (165 MB FETCH / 41 MB WRITE of
// scratch). Fix: `#pragma unroll 1` + a per-pass __syncthreads() (shared-mem
// fence) pins the ds_read_b128s inside each pass. 288 ds_reads/wave total,
// LDS pipe, co-issues with the transcendental stream.
// Stage 1 (redundant per block): mag(d) table via MFMA, A-frags in regs.
// Stage 2: 8 i-rows per block (2 per wave), table-lerp force accumulation.
__launch_bounds__(256, 2)
__global__ void discovery_one(const float* __restrict__ pos,
                              const float* __restrict__ W1,
                              const float* __restrict__ b1,
                              const float* __restrict__ W2,
                              const float* __restrict__ b2,
                              const float* __restrict__ W3,
                              const float* __restrict__ b3,
                              float* __restrict__ out)
{
    __shared__ __align__(16) bf16_t sW[HID * LDH];        // W2^T (34.8 KB, live all of stage 1)
    __shared__ __align__(16) float  tab_s[NPASS * 64 + 4];// 2.3 KB (580 slots, 513 live)
    __shared__ float  pos_s[NPTS * 3];                    // 12 KB
    __shared__ f32x4  w1s[HID];                           // (W1[0,h],W1[1,h],W1[2,h],b1[h])
    __shared__ float  b2s[HID];
    __shared__ float  w3s[HID];

    const int t    = threadIdx.x;       // 0..255
    const int wave = t >> 6;            // 0..3
    const int lane = t & 63;
    const int ln   = lane & 15;
    const int q    = lane >> 4;

    const int b  = blockIdx.x >> 7;     // 128 blocks per batch
    const int ig = blockIdx.x & 127;    // 8 i's per block

    // ---------------- preamble ----------------
    {
        const float4* gp = (const float4*)(pos + b * NPTS * 3);
        float4* sp = (float4*)pos_s;
        for (int idx = t; idx < NPTS * 3 / 4; idx += 256) sp[idx] = gp[idx];
    }
    if (t < HID) {
        f32x4 w = { W1[t], W1[HID + t], W1[2 * HID + t], b1[t] };
        w1s[t] = w;
        b2s[t] = b2[t];
        w3s[t] = W3[t];
    }
    // stage W2 transposed (bf16): sW[n*LDH + k] = W2[k*HID + n]
    for (int idx = t; idx < HID * HID; idx += 256) {
        int k = idx >> 7, n = idx & 127;
        sW[n * LDH + k] = (bf16_t)W2[idx];
    }
    __syncthreads();

    const float dU  = (U1f - U0f) / (float)K_TAB;
    const float b3v = b3[0];
    const bf16_t* wbase = &sW[ln * LDH + q * 8];   // B-frag base for (ln, q)

    // ---------------- Stage 1: table build, 9 passes x 64 entries ----------------
#pragma unroll 1
    for (int p = 0; p < NPASS; ++p) {
        __syncthreads();   // shared-mem fence: forbids hoisting ds_reads out of the loop

        const int base = p * 64 + wave * 16;              // this wave's 16 entries
        // geometry for entry m = ln (clamped beyond K_TAB -> g(U1), never read)
        int   ec   = base + ln; if (ec > K_TAB) ec = K_TAB;
        float u    = U0f + (float)ec * dU;
        float d    = fast_exp2(u);
        float invc = fast_rcp(fmaxf(d, 0.01f));
        float inv2 = invc * invc;

        // A-fragments in registers: afr[ks][j] = tanh-h1[entry ln][unit ks*32+q*8+j]
        bf16x8 afr[4];
#pragma unroll
        for (int ks = 0; ks < 4; ++ks) {
#pragma unroll
            for (int j = 0; j < 8; ++j) {
                f32x4 w = w1s[ks * 32 + q * 8 + j];
                float z = fmaf(d, w[0], fmaf(invc, w[1], fmaf(inv2, w[2], w[3])));
                afr[ks][j] = (bf16_t)fast_tanh(z);
            }
        }

        // h2pre = h1 @ W2 : one 16(entry) x 128(unit) tile per wave.
        // B-frag (nt,ks) read from LDS each pass: sW[(nt*16+ln)*LDH + ks*32 + q*8]
        f32x4 zero = { 0.f, 0.f, 0.f, 0.f };
        f32x4 acc[8];
#pragma unroll
        for (int nt = 0; nt < 8; ++nt) acc[nt] = zero;
#pragma unroll
        for (int ks = 0; ks < 4; ++ks) {
#pragma unroll
            for (int nt = 0; nt < 8; ++nt) {
                bf16x8 bf = *(const bf16x8*)(wbase + (nt * 16) * LDH + ks * 32);
                acc[nt] = __builtin_amdgcn_mfma_f32_16x16x32_bf16(afr[ks], bf, acc[nt], 0, 0, 0);
            }
        }

        // epilogue: tab = tanh(h2pre + b2) @ W3 + b3
        float pm[4] = {0.f, 0.f, 0.f, 0.f};
#pragma unroll
        for (int nt = 0; nt < 8; ++nt) {
            float b2n = b2s[nt * 16 + ln];
            float w3n = w3s[nt * 16 + ln];
#pragma unroll
            for (int r = 0; r < 4; ++r)
                pm[r] += fast_tanh(acc[nt][r] + b2n) * w3n;
        }
#pragma unroll
        for (int off = 1; off < 16; off <<= 1)
#pragma unroll
            for (int r = 0; r < 4; ++r)
                pm[r] += __shfl_xor(pm[r], off);
        if (ln == 0) {
            // C rows q*4+r = entry offsets within this wave's 16-entry group
            f32x4 v = { pm[0] + b3v, pm[1] + b3v, pm[2] + b3v, pm[3] + b3v };
            *(f32x4*)&tab_s[base + q * 4] = v;            // max index 575 < 580
        }
    }
    __syncthreads();   // table complete

    // ---------------- Stage 2: forces (2 i's per wave) ----------------
    const float S  = (float)K_TAB / (U1f - U0f);
    const int   ia = ig * 8 + wave * 2;
    const int   ib = ia + 1;

    const float pax = pos_s[ia * 3 + 0], pay = pos_s[ia * 3 + 1], paz = pos_s[ia * 3 + 2];
    const float pbx = pos_s[ib * 3 + 0], pby = pos_s[ib * 3 + 1], pbz = pos_s[ib * 3 + 2];

    float fax = 0.f, fay = 0.f, faz = 0.f;
    float fbx = 0.f, fby = 0.f, fbz = 0.f;
#pragma unroll 4
    for (int j = lane; j < NPTS; j += 64) {
        float qx = pos_s[j * 3 + 0], qy = pos_s[j * 3 + 1], qz = pos_s[j * 3 + 2];

        float dax = pax - qx, day = pay - qy, daz = paz - qz;
        float dbx = pbx - qx, dby = pby - qy, dbz = pbz - qz;
        float r2a = fmaf(dax, dax, fmaf(day, day, daz * daz));
        float r2b = fmaf(dbx, dbx, fmaf(dby, dby, dbz * dbz));

        float ta = fmaf(0.5f * fast_log2(r2a), S, -U0f * S);  // r2=0 -> -inf -> k=0
        float tb = fmaf(0.5f * fast_log2(r2b), S, -U0f * S);
        float ka = fminf(fmaxf(floorf(ta), 0.0f), (float)(K_TAB - 1));
        float kb = fminf(fmaxf(floorf(tb), 0.0f), (float)(K_TAB - 1));
        float fra = fminf(fmaxf(ta - ka, 0.0f), 1.0f);
        float frb = fminf(fmaxf(tb - kb, 0.0f), 1.0f);
        int ka_i = (int)ka, kb_i = (int)kb;
        float va0 = tab_s[ka_i], va1 = tab_s[ka_i + 1];
        float vb0 = tab_s[kb_i], vb1 = tab_s[kb_i + 1];
        float maga = fmaf(va1 - va0, fra, va0);
        float magb = fmaf(vb1 - vb0, frb, vb0);

        float sa = maga * fminf(fast_rsq(r2a), 100.0f);   // mag/max(d,0.01); rsq(0)=inf->100
        float sb = magb * fminf(fast_rsq(r2b), 100.0f);
        fax = fmaf(sa, dax, fax); fay = fmaf(sa, day, fay); faz = fmaf(sa, daz, faz);
        fbx = fmaf(sb, dbx, fbx); fby = fmaf(sb, dby, fby); fbz = fmaf(sb, dbz, fbz);
    }
#pragma unroll
    for (int off = 1; off < 64; off <<= 1) {
        fax += __shfl_xor(fax, off); fay += __shfl_xor(fay, off); faz += __shfl_xor(faz, off);
        fbx += __shfl_xor(fbx, off); fby += __shfl_xor(fby, off); fbz += __shfl_xor(fbz, off);
    }
    if (lane == 0) {
        int oa = (b * NPTS + ia) * 3;
        int ob = (b * NPTS + ib) * 3;
        out[oa + 0] = fax; out[oa + 1] = fay; out[oa + 2] = faz;
        out[ob + 0] = fbx; out[ob + 1] = fby; out[ob + 2] = fbz;
    }
}

extern "C" void kernel_launch(void* const* d_in, const int* in_sizes, int n_in,
                              void* d_out, int out_size, void* d_ws, size_t ws_size,
                              hipStream_t stream) {
    const float* pos = (const float*)d_in[0];
    const float* W1  = (const float*)d_in[1];
    const float* b1  = (const float*)d_in[2];
    const float* W2  = (const float*)d_in[3];
    const float* b2  = (const float*)d_in[4];
    const float* W3  = (const float*)d_in[5];
    const float* b3  = (const float*)d_in[6];
    float* out = (float*)d_out;

    int B = (in_sizes[0] / 3) / NPTS;
    discovery_one<<<B * 128, 256, 0, stream>>>(pos, W1, b1, W2, b2, W3, b3, out);
}

// Round 13
// 89.316 us; speedup vs baseline: 1.5497x; 1.1566x over previous
//
#include <hip/hip_runtime.h>
#include <hip/hip_bf16.h>

#define NPTS   1024
#define HID    128
#define K_TAB  256            // lerp intervals over u = log2(d) in [U0, U1]
#define NPASS  5              // 5 passes x 64 entries = 320 slots >= K_TAB+1
#define U0f    (-10.0f)
#define U1f    (4.0f)
#define LDH    136            // padded k-stride (bf16) for the W2^T LDS tile

typedef __bf16 bf16_t;
typedef __bf16 bf16x8 __attribute__((ext_vector_type(8)));
typedef float  f32x4  __attribute__((ext_vector_type(4)));

__device__ __forceinline__ float fast_exp2(float x) {
#if __has_builtin(__builtin_amdgcn_exp2f)
    return __builtin_amdgcn_exp2f(x);
#else
    return exp2f(x);
#endif
}
__device__ __forceinline__ float fast_rcp(float x) {
#if __has_builtin(__builtin_amdgcn_rcpf)
    return __builtin_amdgcn_rcpf(x);
#else
    return 1.0f / x;
#endif
}
__device__ __forceinline__ float fast_log2(float x) {
#if __has_builtin(__builtin_amdgcn_logf)
    return __builtin_amdgcn_logf(x);
#else
    return __log2f(x);
#endif
}
__device__ __forceinline__ float fast_rsq(float x) {
#if __has_builtin(__builtin_amdgcn_rsqf)
    return __builtin_amdgcn_rsqf(x);
#else
    return rsqrtf(x);
#endif
}
// tanh(x) = 1 - 2/(e^{2x}+1). Saturates correctly at +-inf.
__device__ __forceinline__ float fast_tanh(float x) {
    float e = fast_exp2(2.8853900817779268f * x);
    return 1.0f - 2.0f * fast_rcp(e + 1.0f);
}

// One plain kernel, no workspace, one graph node.
// 512 blocks (2/CU) x 256 threads (4 waves -> 2 waves/SIMD).
// R12 lesson kept: `#pragma unroll 1` + per-pass __syncthreads() pins the
// B-fragment ds_reads inside the pass loop (otherwise LICM re-creates the
// 128-reg W2 cache and spills: 165 MB scratch traffic in R11).
// R13 change: K_TAB 512 -> 256 (NPASS 9 -> 5). Stage-1 cost is linear in
// table size; at K=512 the lerp error was invisible under bf16-GEMM noise
// (R3 and R7 both absmax 2.0), so 2x coarser stays well under threshold.
__launch_bounds__(256, 2)
__global__ void discovery_one(const float* __restrict__ pos,
                              const float* __restrict__ W1,
                              const float* __restrict__ b1,
                              const float* __restrict__ W2,
                              const float* __restrict__ b2,
                              const float* __restrict__ W3,
                              const float* __restrict__ b3,
                              float* __restrict__ out)
{
    __shared__ __align__(16) bf16_t sW[HID * LDH];        // W2^T (34.8 KB, live all of stage 1)
    __shared__ __align__(16) float  tab_s[NPASS * 64 + 4];// 1.3 KB (324 slots, 257 live)
    __shared__ float  pos_s[NPTS * 3];                    // 12 KB
    __shared__ f32x4  w1s[HID];                           // (W1[0,h],W1[1,h],W1[2,h],b1[h])
    __shared__ float  b2s[HID];
    __shared__ float  w3s[HID];

    const int t    = threadIdx.x;       // 0..255
    const int wave = t >> 6;            // 0..3
    const int lane = t & 63;
    const int ln   = lane & 15;
    const int q    = lane >> 4;

    const int b  = blockIdx.x >> 7;     // 128 blocks per batch
    const int ig = blockIdx.x & 127;    // 8 i's per block

    // ---------------- preamble ----------------
    {
        const float4* gp = (const float4*)(pos + b * NPTS * 3);
        float4* sp = (float4*)pos_s;
        for (int idx = t; idx < NPTS * 3 / 4; idx += 256) sp[idx] = gp[idx];
    }
    if (t < HID) {
        f32x4 w = { W1[t], W1[HID + t], W1[2 * HID + t], b1[t] };
        w1s[t] = w;
        b2s[t] = b2[t];
        w3s[t] = W3[t];
    }
    // stage W2 transposed (bf16): sW[n*LDH + k] = W2[k*HID + n]
    for (int idx = t; idx < HID * HID; idx += 256) {
        int k = idx >> 7, n = idx & 127;
        sW[n * LDH + k] = (bf16_t)W2[idx];
    }
    __syncthreads();

    const float dU  = (U1f - U0f) / (float)K_TAB;
    const float b3v = b3[0];
    const bf16_t* wbase = &sW[ln * LDH + q * 8];   // B-frag base for (ln, q)

    // ---------------- Stage 1: table build, 5 passes x 64 entries ----------------
#pragma unroll 1
    for (int p = 0; p < NPASS; ++p) {
        __syncthreads();   // shared-mem fence: forbids hoisting ds_reads out of the loop

        const int base = p * 64 + wave * 16;              // this wave's 16 entries
        // geometry for entry m = ln (clamped beyond K_TAB -> g(U1), never read)
        int   ec   = base + ln; if (ec > K_TAB) ec = K_TAB;
        float u    = U0f + (float)ec * dU;
        float d    = fast_exp2(u);
        float invc = fast_rcp(fmaxf(d, 0.01f));
        float inv2 = invc * invc;

        // A-fragments in registers: afr[ks][j] = tanh-h1[entry ln][unit ks*32+q*8+j]
        bf16x8 afr[4];
#pragma unroll
        for (int ks = 0; ks < 4; ++ks) {
#pragma unroll
            for (int j = 0; j < 8; ++j) {
                f32x4 w = w1s[ks * 32 + q * 8 + j];
                float z = fmaf(d, w[0], fmaf(invc, w[1], fmaf(inv2, w[2], w[3])));
                afr[ks][j] = (bf16_t)fast_tanh(z);
            }
        }

        // h2pre = h1 @ W2 : one 16(entry) x 128(unit) tile per wave.
        // B-frag (nt,ks) read from LDS each pass: sW[(nt*16+ln)*LDH + ks*32 + q*8]
        f32x4 zero = { 0.f, 0.f, 0.f, 0.f };
        f32x4 acc[8];
#pragma unroll
        for (int nt = 0; nt < 8; ++nt) acc[nt] = zero;
#pragma unroll
        for (int ks = 0; ks < 4; ++ks) {
#pragma unroll
            for (int nt = 0; nt < 8; ++nt) {
                bf16x8 bf = *(const bf16x8*)(wbase + (nt * 16) * LDH + ks * 32);
                acc[nt] = __builtin_amdgcn_mfma_f32_16x16x32_bf16(afr[ks], bf, acc[nt], 0, 0, 0);
            }
        }

        // epilogue: tab = tanh(h2pre + b2) @ W3 + b3
        float pm[4] = {0.f, 0.f, 0.f, 0.f};
#pragma unroll
        for (int nt = 0; nt < 8; ++nt) {
            float b2n = b2s[nt * 16 + ln];
            float w3n = w3s[nt * 16 + ln];
#pragma unroll
            for (int r = 0; r < 4; ++r)
                pm[r] += fast_tanh(acc[nt][r] + b2n) * w3n;
        }
#pragma unroll
        for (int off = 1; off < 16; off <<= 1)
#pragma unroll
            for (int r = 0; r < 4; ++r)
                pm[r] += __shfl_xor(pm[r], off);
        if (ln == 0) {
            // C rows q*4+r = entry offsets within this wave's 16-entry group
            f32x4 v = { pm[0] + b3v, pm[1] + b3v, pm[2] + b3v, pm[3] + b3v };
            *(f32x4*)&tab_s[base + q * 4] = v;            // max index 319 < 324
        }
    }
    __syncthreads();   // table complete

    // ---------------- Stage 2: forces (2 i's per wave) ----------------
    const float S  = (float)K_TAB / (U1f - U0f);
    const int   ia = ig * 8 + wave * 2;
    const int   ib = ia + 1;

    const float pax = pos_s[ia * 3 + 0], pay = pos_s[ia * 3 + 1], paz = pos_s[ia * 3 + 2];
    const float pbx = pos_s[ib * 3 + 0], pby = pos_s[ib * 3 + 1], pbz = pos_s[ib * 3 + 2];

    float fax = 0.f, fay = 0.f, faz = 0.f;
    float fbx = 0.f, fby = 0.f, fbz = 0.f;
#pragma unroll 4
    for (int j = lane; j < NPTS; j += 64) {
        float qx = pos_s[j * 3 + 0], qy = pos_s[j * 3 + 1], qz = pos_s[j * 3 + 2];

        float dax = pax - qx, day = pay - qy, daz = paz - qz;
        float dbx = pbx - qx, dby = pby - qy, dbz = pbz - qz;
        float r2a = fmaf(dax, dax, fmaf(day, day, daz * daz));
        float r2b = fmaf(dbx, dbx, fmaf(dby, dby, dbz * dbz));

        float ta = fmaf(0.5f * fast_log2(r2a), S, -U0f * S);  // r2=0 -> -inf -> k=0
        float tb = fmaf(0.5f * fast_log2(r2b), S, -U0f * S);
        float ka = fminf(fmaxf(floorf(ta), 0.0f), (float)(K_TAB - 1));
        float kb = fminf(fmaxf(floorf(tb), 0.0f), (float)(K_TAB - 1));
        float fra = fminf(fmaxf(ta - ka, 0.0f), 1.0f);
        float frb = fminf(fmaxf(tb - kb, 0.0f), 1.0f);
        int ka_i = (int)ka, kb_i = (int)kb;
        float va0 = tab_s[ka_i], va1 = tab_s[ka_i + 1];
        float vb0 = tab_s[kb_i], vb1 = tab_s[kb_i + 1];
        float maga = fmaf(va1 - va0, fra, va0);
        float magb = fmaf(vb1 - vb0, frb, vb0);

        float sa = maga * fminf(fast_rsq(r2a), 100.0f);   // mag/max(d,0.01); rsq(0)=inf->100
        float sb = magb * fminf(fast_rsq(r2b), 100.0f);
        fax = fmaf(sa, dax, fax); fay = fmaf(sa, day, fay); faz = fmaf(sa, daz, faz);
        fbx = fmaf(sb, dbx, fbx); fby = fmaf(sb, dby, fby); fbz = fmaf(sb, dbz, fbz);
    }
#pragma unroll
    for (int off = 1; off < 64; off <<= 1) {
        fax += __shfl_xor(fax, off); fay += __shfl_xor(fay, off); faz += __shfl_xor(faz, off);
        fbx += __shfl_xor(fbx, off); fby += __shfl_xor(fby, off); fbz += __shfl_xor(fbz, off);
    }
    if (lane == 0) {
        int oa = (b * NPTS + ia) * 3;
        int ob = (b * NPTS + ib) * 3;
        out[oa + 0] = fax; out[oa + 1] = fay; out[oa + 2] = faz;
        out[ob + 0] = fbx; out[ob + 1] = fby; out[ob + 2] = fbz;
    }
}

extern "C" void kernel_launch(void* const* d_in, const int* in_sizes, int n_in,
                              void* d_out, int out_size, void* d_ws, size_t ws_size,
                              hipStream_t stream) {
    const float* pos = (const float*)d_in[0];
    const float* W1  = (const float*)d_in[1];
    const float* b1  = (const float*)d_in[2];
    const float* W2  = (const float*)d_in[3];
    const float* b2  = (const float*)d_in[4];
    const float* W3  = (const float*)d_in[5];
    const float* b3  = (const float*)d_in[6];
    float* out = (float*)d_out;

    int B = (in_sizes[0] / 3) / NPTS;
    discovery_one<<<B * 128, 256, 0, stream>>>(pos, W1, b1, W2, b2, W3, b3, out);
}